// Round 1
// baseline (328.076 us; speedup 1.0000x reference)
//
#include <hip/hip_runtime.h>

// VQ pairwise L2 distance: out[n,k] = || X[n,:] - E[k,:] ||_2
// N=65536, K=1024, D=64. fp32 in/out; cross-term via bf16 MFMA
// (16x16x32), x_sq/e_sq computed from the SAME bf16-rounded values so the
// result is exactly ||x~ - e~|| (error ~ ||x|| * 2^-9 ~= 0.02 << 0.23 thr).

typedef __attribute__((ext_vector_type(8))) short short8;    // 8 bf16 = 4 VGPR
typedef __attribute__((ext_vector_type(4))) float floatx4;   // MFMA C/D

#define LSTR 72  // LDS row stride in bf16 elements: 64 + 8 pad -> 2-way bank alias (free)

__device__ inline unsigned short f2bf(float f) {
    // round-to-nearest-even fp32 -> bf16 (inputs are finite normals)
    unsigned int u = __float_as_uint(f);
    u += 0x7FFFu + ((u >> 16) & 1u);
    return (unsigned short)(u >> 16);
}
__device__ inline float bf2f(unsigned short h) {
    return __uint_as_float(((unsigned int)h) << 16);
}

__global__ __launch_bounds__(256) void vq_dist(const float* __restrict__ X,
                                               const float* __restrict__ E,
                                               float* __restrict__ out,
                                               int Ktot) {
    __shared__ unsigned short lA[128 * LSTR];
    __shared__ unsigned short lB[128 * LSTR];
    __shared__ float s_xsq[128];
    __shared__ float s_esq[128];

    const int tid = threadIdx.x;
    const size_t m0 = (size_t)blockIdx.y * 128;   // x-row tile base
    const int n0 = blockIdx.x * 128;              // codebook tile base

    // ---- stage X tile and E tile (fp32 -> bf16) + per-row sum of squares ----
    {
        const int r8 = tid >> 3;        // 0..31 : row within 32-row slab
        const int c8 = (tid & 7) * 8;   // 0..56 : 8 floats per thread
        #pragma unroll
        for (int it = 0; it < 4; ++it) {
            const int row = it * 32 + r8;
            // ---- A (inputs) ----
            {
                const float* src = X + (m0 + row) * 64 + c8;
                float4 v0 = *(const float4*)src;
                float4 v1 = *(const float4*)(src + 4);
                unsigned short h[8] = {f2bf(v0.x), f2bf(v0.y), f2bf(v0.z), f2bf(v0.w),
                                       f2bf(v1.x), f2bf(v1.y), f2bf(v1.z), f2bf(v1.w)};
                float s = 0.f;
                short8 pk;
                #pragma unroll
                for (int j = 0; j < 8; ++j) {
                    float f = bf2f(h[j]);
                    s = fmaf(f, f, s);
                    pk[j] = (short)h[j];
                }
                *(short8*)&lA[row * LSTR + c8] = pk;
                s += __shfl_down(s, 4, 8);
                s += __shfl_down(s, 2, 8);
                s += __shfl_down(s, 1, 8);
                if ((tid & 7) == 0) s_xsq[row] = s;
            }
            // ---- B (embeddings) ----
            {
                const float* src = E + (size_t)(n0 + row) * 64 + c8;
                float4 v0 = *(const float4*)src;
                float4 v1 = *(const float4*)(src + 4);
                unsigned short h[8] = {f2bf(v0.x), f2bf(v0.y), f2bf(v0.z), f2bf(v0.w),
                                       f2bf(v1.x), f2bf(v1.y), f2bf(v1.z), f2bf(v1.w)};
                float s = 0.f;
                short8 pk;
                #pragma unroll
                for (int j = 0; j < 8; ++j) {
                    float f = bf2f(h[j]);
                    s = fmaf(f, f, s);
                    pk[j] = (short)h[j];
                }
                *(short8*)&lB[row * LSTR + c8] = pk;
                s += __shfl_down(s, 4, 8);
                s += __shfl_down(s, 2, 8);
                s += __shfl_down(s, 1, 8);
                if ((tid & 7) == 0) s_esq[row] = s;
            }
        }
    }
    __syncthreads();

    // ---- MFMA: each of 4 waves computes a 64x64 subtile (2x2 wave grid) ----
    const int w = tid >> 6;
    const int lane = tid & 63;
    const int quad = lane >> 4;
    const int l16 = lane & 15;
    const int wm = (w >> 1) * 64;  // wave row offset in 128-tile
    const int wn = (w & 1) * 64;   // wave col offset

    // A frag: A[m = l16][k = quad*8 + j]; B frag (B^T layout): E[n = l16][k = quad*8 + j]
    short8 a0[4], a1[4], b0[4], b1[4];
    #pragma unroll
    for (int t = 0; t < 4; ++t) {
        const int ar = wm + t * 16 + l16;
        a0[t] = *(const short8*)&lA[ar * LSTR + quad * 8];
        a1[t] = *(const short8*)&lA[ar * LSTR + 32 + quad * 8];
        const int br = wn + t * 16 + l16;
        b0[t] = *(const short8*)&lB[br * LSTR + quad * 8];
        b1[t] = *(const short8*)&lB[br * LSTR + 32 + quad * 8];
    }

    floatx4 acc[4][4];
    #pragma unroll
    for (int i = 0; i < 4; ++i)
        #pragma unroll
        for (int j = 0; j < 4; ++j)
            acc[i][j] = (floatx4){0.f, 0.f, 0.f, 0.f};

    #pragma unroll
    for (int i = 0; i < 4; ++i)
        #pragma unroll
        for (int j = 0; j < 4; ++j) {
            acc[i][j] = __builtin_amdgcn_mfma_f32_16x16x32_bf16(a0[i], b0[j], acc[i][j], 0, 0, 0);
            acc[i][j] = __builtin_amdgcn_mfma_f32_16x16x32_bf16(a1[i], b1[j], acc[i][j], 0, 0, 0);
        }

    // ---- epilogue: d = sqrt(max(xsq + esq - 2*cross, 0)) ----
    // C/D layout: col = l16, row = quad*4 + r  [verified m89/m91]
    #pragma unroll
    for (int i = 0; i < 4; ++i) {
        const int mrow = wm + i * 16 + quad * 4;
        float xq[4];
        #pragma unroll
        for (int r = 0; r < 4; ++r) xq[r] = s_xsq[mrow + r];
        #pragma unroll
        for (int j = 0; j < 4; ++j) {
            const int ncol = wn + j * 16 + l16;
            const float eq = s_esq[ncol];
            float* op = out + (m0 + mrow) * Ktot + (n0 + ncol);
            #pragma unroll
            for (int r = 0; r < 4; ++r) {
                float d = xq[r] + eq - 2.0f * acc[i][j][r];
                d = fmaxf(d, 0.0f);
                op[(size_t)r * Ktot] = sqrtf(d);
            }
        }
    }
}

extern "C" void kernel_launch(void* const* d_in, const int* in_sizes, int n_in,
                              void* d_out, int out_size, void* d_ws, size_t ws_size,
                              hipStream_t stream) {
    const float* X = (const float*)d_in[0];
    const float* E = (const float*)d_in[1];
    float* out = (float*)d_out;
    const int N = in_sizes[0] / 64;   // 65536
    const int K = in_sizes[1] / 64;   // 1024
    dim3 grid(K / 128, N / 128);      // (8, 512)
    vq_dist<<<grid, dim3(256), 0, stream>>>(X, E, out, K);
}

// Round 2
// 309.058 us; speedup vs baseline: 1.0615x; 1.0615x over previous
//
#include <hip/hip_runtime.h>

// VQ pairwise L2: out[n,k] = ||X[n,:] - E[k,:]||, N=65536 K=1024 D=64.
// Two-pass: prep converts fp32 -> bf16 (pre-padded to LDS stride 72) + norms
// into d_ws; main kernel stages via global_load_lds dwordx4, 16x16x32 bf16
// MFMA cross-term, nontemporal fp32 stores.

typedef __attribute__((ext_vector_type(8))) short short8;    // 8 bf16 = 4 VGPR
typedef __attribute__((ext_vector_type(4))) float floatx4;   // MFMA C/D

typedef __attribute__((address_space(3))) unsigned int lds_u32;
typedef __attribute__((address_space(1))) const unsigned int glb_u32;

#define LSTR 72          // padded row stride in bf16 elems (144 B)
#define N_ROWS 65536
#define K_ROWS 1024

// ws byte offsets
#define WS_XB  0u
#define WS_EB  9437184u          // 65536*144
#define WS_XSQ 9584640u          // + 1024*144
#define WS_ESQ 9846784u          // + 65536*4

__device__ __forceinline__ unsigned short f2bf(float f) {
    unsigned int u = __float_as_uint(f);
    u += 0x7FFFu + ((u >> 16) & 1u);
    return (unsigned short)(u >> 16);
}
__device__ __forceinline__ float bf2f(unsigned short h) {
    return __uint_as_float(((unsigned int)h) << 16);
}

// ---- pass 1: fp32 -> bf16 (padded stride 72) + row sum-of-squares ----
// 8 threads per row; grid covers N+K rows exactly.
__global__ __launch_bounds__(256) void vq_prep(const float* __restrict__ X,
                                               const float* __restrict__ E,
                                               unsigned short* __restrict__ Xb,
                                               unsigned short* __restrict__ Eb,
                                               float* __restrict__ xsq,
                                               float* __restrict__ esq) {
    const int t = blockIdx.x * 256 + threadIdx.x;
    const int row = t >> 3;
    const int c8 = (t & 7) * 8;
    const float* src;
    unsigned short* dst;
    float* sq;
    int r;
    if (row < N_ROWS) {
        r = row;
        src = X + (size_t)r * 64 + c8;
        dst = Xb + (size_t)r * LSTR + c8;
        sq = xsq;
    } else {
        r = row - N_ROWS;
        src = E + (size_t)r * 64 + c8;
        dst = Eb + (size_t)r * LSTR + c8;
        sq = esq;
    }
    float4 v0 = *(const float4*)src;
    float4 v1 = *(const float4*)(src + 4);
    unsigned short h[8] = {f2bf(v0.x), f2bf(v0.y), f2bf(v0.z), f2bf(v0.w),
                           f2bf(v1.x), f2bf(v1.y), f2bf(v1.z), f2bf(v1.w)};
    float s = 0.f;
    short8 pk;
    #pragma unroll
    for (int j = 0; j < 8; ++j) {
        float f = bf2f(h[j]);
        s = fmaf(f, f, s);
        pk[j] = (short)h[j];
    }
    *(short8*)dst = pk;
    s += __shfl_down(s, 4, 8);
    s += __shfl_down(s, 2, 8);
    s += __shfl_down(s, 1, 8);
    if ((t & 7) == 0) sq[r] = s;
}

// ---- pass 2: 128x128 tile, async-staged bf16, MFMA, sqrt epilogue ----
__global__ __launch_bounds__(256) void vq_main(const unsigned short* __restrict__ Xb,
                                               const unsigned short* __restrict__ Eb,
                                               const float* __restrict__ xsq,
                                               const float* __restrict__ esq,
                                               float* __restrict__ out,
                                               int Ktot) {
    __shared__ unsigned short lds[2 * 128 * LSTR];   // A tile then B tile, 36864 B
    __shared__ float s_xsq[128];
    __shared__ float s_esq[128];

    const int tid = threadIdx.x;
    const int w = tid >> 6;
    const int lane = tid & 63;
    const size_t m0 = (size_t)blockIdx.y * 128;
    const int n0 = blockIdx.x * 128;

    // stage A (18432 B) + B (18432 B) as 36 x 1 KiB chunks, 9 per wave,
    // via direct global->LDS DMA (LDS dest = chunk base + lane*16).
    const char* srcA = (const char*)(Xb + m0 * LSTR);
    const char* srcB = (const char*)(Eb + (size_t)n0 * LSTR);
    #pragma unroll
    for (int c = 0; c < 9; ++c) {
        const int chunk = w * 9 + c;
        const int off = chunk * 1024 + lane * 16;
        const char* g = (chunk < 18) ? (srcA + off) : (srcB + (off - 18432));
        __builtin_amdgcn_global_load_lds((glb_u32*)g,
                                         (lds_u32*)((char*)lds + chunk * 1024),
                                         16, 0, 0);
    }
    if (tid < 128) s_xsq[tid] = xsq[m0 + tid];
    else           s_esq[tid - 128] = esq[n0 + tid - 128];
    __syncthreads();

    const unsigned short* lA = lds;
    const unsigned short* lB = lds + 128 * LSTR;

    const int quad = lane >> 4;
    const int l16 = lane & 15;
    const int wm = (w >> 1) * 64;
    const int wn = (w & 1) * 64;

    short8 a0[4], a1[4], b0[4], b1[4];
    #pragma unroll
    for (int t = 0; t < 4; ++t) {
        const int ar = wm + t * 16 + l16;
        a0[t] = *(const short8*)&lA[ar * LSTR + quad * 8];
        a1[t] = *(const short8*)&lA[ar * LSTR + 32 + quad * 8];
        const int br = wn + t * 16 + l16;
        b0[t] = *(const short8*)&lB[br * LSTR + quad * 8];
        b1[t] = *(const short8*)&lB[br * LSTR + 32 + quad * 8];
    }

    floatx4 acc[4][4];
    #pragma unroll
    for (int i = 0; i < 4; ++i)
        #pragma unroll
        for (int j = 0; j < 4; ++j)
            acc[i][j] = (floatx4){0.f, 0.f, 0.f, 0.f};

    #pragma unroll
    for (int i = 0; i < 4; ++i)
        #pragma unroll
        for (int j = 0; j < 4; ++j) {
            acc[i][j] = __builtin_amdgcn_mfma_f32_16x16x32_bf16(a0[i], b0[j], acc[i][j], 0, 0, 0);
            acc[i][j] = __builtin_amdgcn_mfma_f32_16x16x32_bf16(a1[i], b1[j], acc[i][j], 0, 0, 0);
        }

    // epilogue: d = sqrt(max(xsq + esq - 2*cross, 0)); C/D: col=l16, row=quad*4+r
    #pragma unroll
    for (int i = 0; i < 4; ++i) {
        const int mrow = wm + i * 16 + quad * 4;
        float xq[4];
        #pragma unroll
        for (int r = 0; r < 4; ++r) xq[r] = s_xsq[mrow + r];
        #pragma unroll
        for (int j = 0; j < 4; ++j) {
            const int ncol = wn + j * 16 + l16;
            const float eq = s_esq[ncol];
            float* op = out + (m0 + mrow) * Ktot + (n0 + ncol);
            #pragma unroll
            for (int r = 0; r < 4; ++r) {
                float d = xq[r] + eq - 2.0f * acc[i][j][r];
                d = fmaxf(d, 0.0f);
                __builtin_nontemporal_store(sqrtf(d), op + (size_t)r * Ktot);
            }
        }
    }
}

extern "C" void kernel_launch(void* const* d_in, const int* in_sizes, int n_in,
                              void* d_out, int out_size, void* d_ws, size_t ws_size,
                              hipStream_t stream) {
    const float* X = (const float*)d_in[0];
    const float* E = (const float*)d_in[1];
    float* out = (float*)d_out;
    const int K = in_sizes[1] / 64;   // 1024

    char* ws = (char*)d_ws;
    unsigned short* Xb = (unsigned short*)(ws + WS_XB);
    unsigned short* Eb = (unsigned short*)(ws + WS_EB);
    float* xsq = (float*)(ws + WS_XSQ);
    float* esq = (float*)(ws + WS_ESQ);

    // pass 1: (N+K) rows * 8 threads = 532480 threads = 2080 blocks of 256
    vq_prep<<<dim3((N_ROWS + K_ROWS) * 8 / 256), dim3(256), 0, stream>>>(X, E, Xb, Eb, xsq, esq);

    // pass 2
    dim3 grid(K / 128, N_ROWS / 128);   // (8, 512)
    vq_main<<<grid, dim3(256), 0, stream>>>(Xb, Eb, xsq, esq, out, K);
}